// Round 1
// baseline (568.416 us; speedup 1.0000x reference)
//
#include <hip/hip_runtime.h>

// ---------------------------------------------------------------------------
// 2-layer GCN: out = GCNConv2( relu(GCNConv1(x)) )
// GCNConv(x,W,b): h = x@W ; out[d] = dinv[d]*( sum_{s->d} h[s]*dinv[s] + h[d]*dinv[d] ) + b
// with dinv = rsqrt(in-degree + 1)  (self-loops added).
// ---------------------------------------------------------------------------

// Detect whether edge_index was stored as int64 (all high words of values <N
// are zero) or int32 (odd words are random node ids, nonzero w.h.p.).
__global__ void detect_i64_kernel(const unsigned int* __restrict__ w, int ncheck,
                                  int* __restrict__ flag) {
  __shared__ int nz;
  if (threadIdx.x == 0) nz = 0;
  __syncthreads();
  for (int i = threadIdx.x; i < ncheck; i += blockDim.x) {
    if (w[2 * i + 1] != 0u) nz = 1;
  }
  __syncthreads();
  if (threadIdx.x == 0) flag[0] = (nz == 0) ? 1 : 0;
}

// counts[d] += 1 for every edge dst d
__global__ void count_kernel(const int* __restrict__ edges, int E,
                             const int* __restrict__ flag, int* __restrict__ counts) {
  const int f = flag[0];
  const int stride = gridDim.x * blockDim.x;
  for (int e = blockIdx.x * blockDim.x + threadIdx.x; e < E; e += stride) {
    int d = f ? edges[2 * ((size_t)E + e)] : edges[(size_t)E + e];
    atomicAdd(&counts[d], 1);
  }
}

// Exclusive scan of counts[0..n) -> row_ptr[0..n], single block of 1024.
__global__ void scan_kernel(const int* __restrict__ counts, int* __restrict__ row_ptr, int n) {
  __shared__ int sm[1024];
  __shared__ int carry_s;
  if (threadIdx.x == 0) { carry_s = 0; row_ptr[0] = 0; }
  __syncthreads();
  for (int base = 0; base < n; base += 1024) {
    int i = base + (int)threadIdx.x;
    int v = (i < n) ? counts[i] : 0;
    sm[threadIdx.x] = v;
    __syncthreads();
    for (int off = 1; off < 1024; off <<= 1) {
      int t = (threadIdx.x >= (unsigned)off) ? sm[threadIdx.x - off] : 0;
      __syncthreads();
      sm[threadIdx.x] += t;
      __syncthreads();
    }
    int incl = sm[threadIdx.x] + carry_s;
    if (i < n) row_ptr[i + 1] = incl;
    __syncthreads();
    if (threadIdx.x == 1023) carry_s = incl;
    __syncthreads();
  }
}

// dinv = rsqrt(count+1); cursor = row_ptr (fill cursors)
__global__ void dinv_cursor_kernel(const int* __restrict__ counts,
                                   const int* __restrict__ row_ptr,
                                   float* __restrict__ dinv, int* __restrict__ cursor, int n) {
  int i = blockIdx.x * blockDim.x + threadIdx.x;
  if (i < n) {
    dinv[i] = rsqrtf((float)(counts[i] + 1));
    cursor[i] = row_ptr[i];
  }
}

// Scatter edges into CSR-by-dst (stores src ids)
__global__ void fill_kernel(const int* __restrict__ edges, int E,
                            const int* __restrict__ flag,
                            int* __restrict__ cursor, int* __restrict__ csr) {
  const int f = flag[0];
  const int stride = gridDim.x * blockDim.x;
  for (int e = blockIdx.x * blockDim.x + threadIdx.x; e < E; e += stride) {
    int s, d;
    if (f) { s = edges[2 * (size_t)e]; d = edges[2 * ((size_t)E + e)]; }
    else   { s = edges[e];             d = edges[(size_t)E + e]; }
    int pos = atomicAdd(&cursor[d], 1);
    csr[pos] = s;
  }
}

// out[r][c] = (sum_k A[r][k]*W[k][c]) * dinv[r]    (A: n x K, W: K x 64)
// 64x64 tile per 256-thread block, 4x4 register blocking, K-chunks of 32.
template <int K>
__global__ __launch_bounds__(256) void gemm_scale_kernel(
    const float* __restrict__ A, const float* __restrict__ W,
    const float* __restrict__ dinv, float* __restrict__ out, int n) {
  __shared__ float As[32][68];  // As[k][row]  (transposed stage, pad to 68)
  __shared__ float Bs[32][68];  // Bs[k][col]
  const int t = threadIdx.x;
  const int tr = t >> 4;        // 0..15 row group (rows tr*4..tr*4+3)
  const int tc = t & 15;        // 0..15 col group (cols tc*4..tc*4+3)
  const int row0 = blockIdx.x * 64;
  const int sr = t >> 2;        // 0..63 : row for A staging
  const int sk = (t & 3) << 3;  // 0,8,16,24 : k offset for A staging
  const int wkk = t >> 3;       // 0..31 : k for W staging
  const int wc = (t & 7) << 3;  // 0,8,..56 : col offset for W staging

  float acc[4][4] = {{0.f, 0.f, 0.f, 0.f}, {0.f, 0.f, 0.f, 0.f},
                     {0.f, 0.f, 0.f, 0.f}, {0.f, 0.f, 0.f, 0.f}};

  for (int k0 = 0; k0 < K; k0 += 32) {
    float4 a0 = make_float4(0.f, 0.f, 0.f, 0.f), a1 = a0;
    int r = row0 + sr;
    if (r < n) {
      a0 = *(const float4*)&A[(size_t)r * K + k0 + sk];
      a1 = *(const float4*)&A[(size_t)r * K + k0 + sk + 4];
    }
    float4 w0 = *(const float4*)&W[(size_t)(k0 + wkk) * 64 + wc];
    float4 w1 = *(const float4*)&W[(size_t)(k0 + wkk) * 64 + wc + 4];
    if (k0 != 0) __syncthreads();  // previous compute done before restaging
    As[sk + 0][sr] = a0.x; As[sk + 1][sr] = a0.y; As[sk + 2][sr] = a0.z; As[sk + 3][sr] = a0.w;
    As[sk + 4][sr] = a1.x; As[sk + 5][sr] = a1.y; As[sk + 6][sr] = a1.z; As[sk + 7][sr] = a1.w;
    *(float4*)&Bs[wkk][wc] = w0;
    *(float4*)&Bs[wkk][wc + 4] = w1;
    __syncthreads();
#pragma unroll
    for (int kk = 0; kk < 32; ++kk) {
      float4 a4 = *(const float4*)&As[kk][tr << 2];
      float4 b4 = *(const float4*)&Bs[kk][tc << 2];
      float av[4] = {a4.x, a4.y, a4.z, a4.w};
      float bv[4] = {b4.x, b4.y, b4.z, b4.w};
#pragma unroll
      for (int i = 0; i < 4; ++i)
#pragma unroll
        for (int j = 0; j < 4; ++j)
          acc[i][j] = fmaf(av[i], bv[j], acc[i][j]);
    }
  }
  __syncthreads();

#pragma unroll
  for (int i = 0; i < 4; ++i) {
    int r = row0 + (tr << 2) + i;
    if (r < n) {
      float s = dinv[r];
      float4 o;
      o.x = acc[i][0] * s; o.y = acc[i][1] * s;
      o.z = acc[i][2] * s; o.w = acc[i][3] * s;
      *(float4*)&out[(size_t)r * 64 + (tc << 2)] = o;
    }
  }
}

// One wave per dst node, lane = channel. acc = hs[d] (self loop) + sum hs[src].
// out = acc*dinv[d] + bias, optional relu.
template <int RELU>
__global__ __launch_bounds__(256) void agg_kernel(
    const float* __restrict__ hs, const int* __restrict__ row_ptr,
    const int* __restrict__ csr, const float* __restrict__ dinv,
    const float* __restrict__ bias, float* __restrict__ out, int n) {
  const int wave = blockIdx.x * 4 + ((int)threadIdx.x >> 6);
  const int lane = (int)threadIdx.x & 63;
  if (wave >= n) return;
  const int d = wave;
  const int start = row_ptr[d];
  const int end = row_ptr[d + 1];
  float acc = hs[(size_t)d * 64 + lane];  // self loop contribution
  int j = start;
  for (; j + 4 <= end; j += 4) {
    int s0 = csr[j], s1 = csr[j + 1], s2 = csr[j + 2], s3 = csr[j + 3];
    float v0 = hs[(size_t)s0 * 64 + lane];
    float v1 = hs[(size_t)s1 * 64 + lane];
    float v2 = hs[(size_t)s2 * 64 + lane];
    float v3 = hs[(size_t)s3 * 64 + lane];
    acc += v0; acc += v1; acc += v2; acc += v3;
  }
  for (; j < end; ++j) acc += hs[(size_t)csr[j] * 64 + lane];
  float v = acc * dinv[d] + bias[lane];
  if (RELU) v = fmaxf(v, 0.f);
  out[(size_t)d * 64 + lane] = v;
}

extern "C" void kernel_launch(void* const* d_in, const int* in_sizes, int n_in,
                              void* d_out, int out_size, void* d_ws, size_t ws_size,
                              hipStream_t stream) {
  const float* x  = (const float*)d_in[0];
  const int*   ei = (const int*)d_in[1];
  const float* W1 = (const float*)d_in[2];
  const float* b1 = (const float*)d_in[3];
  const float* W2 = (const float*)d_in[4];
  const float* b2 = (const float*)d_in[5];
  float* out = (float*)d_out;

  const int N = in_sizes[0] / 128;  // 100000
  const int E = in_sizes[1] / 2;    // 1600000 (element count is dtype-agnostic)

  char* ws = (char*)d_ws;
  size_t off = 0;
  auto take = [&](size_t bytes) -> void* {
    void* p = ws + off;
    off += (bytes + 255) & ~(size_t)255;
    return p;
  };
  int*   flag    = (int*)take(sizeof(int));
  int*   counts  = (int*)take((size_t)N * 4);
  int*   row_ptr = (int*)take((size_t)(N + 1) * 4);
  int*   cursor  = (int*)take((size_t)N * 4);
  float* dinv    = (float*)take((size_t)N * 4);
  int*   csr     = (int*)take((size_t)E * 4);
  float* bufA    = (float*)take((size_t)N * 64 * 4);  // hs (scaled GEMM out)
  float* bufB    = (float*)take((size_t)N * 64 * 4);  // h (post layer-1)
  (void)ws_size; (void)n_in; (void)out_size;

  (void)hipMemsetAsync(counts, 0, (size_t)N * 4, stream);
  detect_i64_kernel<<<1, 256, 0, stream>>>((const unsigned int*)ei, 4096, flag);
  count_kernel<<<2048, 256, 0, stream>>>(ei, E, flag, counts);
  scan_kernel<<<1, 1024, 0, stream>>>(counts, row_ptr, N);
  dinv_cursor_kernel<<<(N + 255) / 256, 256, 0, stream>>>(counts, row_ptr, dinv, cursor, N);
  fill_kernel<<<2048, 256, 0, stream>>>(ei, E, flag, cursor, csr);

  // Layer 1: hs1 = (x @ W1) * dinv ; h = relu(dinv*(agg) + b1)
  gemm_scale_kernel<128><<<(N + 63) / 64, 256, 0, stream>>>(x, W1, dinv, bufA, N);
  agg_kernel<1><<<(N + 3) / 4, 256, 0, stream>>>(bufA, row_ptr, csr, dinv, b1, bufB, N);

  // Layer 2: hs2 = (h @ W2) * dinv ; out = dinv*(agg) + b2
  gemm_scale_kernel<64><<<(N + 63) / 64, 256, 0, stream>>>(bufB, W2, dinv, bufA, N);
  agg_kernel<0><<<(N + 3) / 4, 256, 0, stream>>>(bufA, row_ptr, csr, dinv, b2, out, N);
}

// Round 2
// 404.807 us; speedup vs baseline: 1.4042x; 1.4042x over previous
//
#include <hip/hip_runtime.h>

// ---------------------------------------------------------------------------
// 2-layer GCN: out = GCNConv2( relu(GCNConv1(x)) )
// GCNConv(x,W,b): h = x@W ; out[d] = dinv[d]*( sum_{s->d} h[s]*dinv[s] + h[d]*dinv[d] ) + b
// with dinv = rsqrt(in-degree + 1)  (self-loops added).
// ---------------------------------------------------------------------------

// Detect whether edge_index was stored as int64 (all high words of values <N
// are zero) or int32 (odd words are random node ids, nonzero w.h.p.).
__global__ void detect_i64_kernel(const unsigned int* __restrict__ w, int ncheck,
                                  int* __restrict__ flag) {
  __shared__ int nz;
  if (threadIdx.x == 0) nz = 0;
  __syncthreads();
  for (int i = threadIdx.x; i < ncheck; i += blockDim.x) {
    if (w[2 * i + 1] != 0u) nz = 1;
  }
  __syncthreads();
  if (threadIdx.x == 0) flag[0] = (nz == 0) ? 1 : 0;
}

// counts[d] += 1 for every edge dst d
__global__ void count_kernel(const int* __restrict__ edges, int E,
                             const int* __restrict__ flag, int* __restrict__ counts) {
  const int f = flag[0];
  const int stride = gridDim.x * blockDim.x;
  for (int e = blockIdx.x * blockDim.x + threadIdx.x; e < E; e += stride) {
    int d = f ? edges[2 * ((size_t)E + e)] : edges[(size_t)E + e];
    atomicAdd(&counts[d], 1);
  }
}

// ---- 3-phase device-wide exclusive scan over counts[0..n) ------------------
// chunk = 2048 elements / block (256 threads x 8).

__global__ __launch_bounds__(256) void partial_sum_kernel(
    const int* __restrict__ counts, int n, int* __restrict__ partials) {
  const int base = blockIdx.x * 2048 + (int)threadIdx.x * 8;
  int s = 0;
#pragma unroll
  for (int k = 0; k < 8; ++k) {
    int i = base + k;
    if (i < n) s += counts[i];
  }
#pragma unroll
  for (int off = 32; off; off >>= 1) s += __shfl_down(s, off, 64);
  __shared__ int ws[4];
  if ((threadIdx.x & 63) == 0) ws[threadIdx.x >> 6] = s;
  __syncthreads();
  if (threadIdx.x == 0) partials[blockIdx.x] = ws[0] + ws[1] + ws[2] + ws[3];
}

// single block, nb <= 256: partials[i] <- sum of partials[0..i)
__global__ __launch_bounds__(256) void scan_partials_kernel(int* __restrict__ partials, int nb) {
  __shared__ int sm[256];
  const int t = threadIdx.x;
  int v = (t < nb) ? partials[t] : 0;
  sm[t] = v;
  __syncthreads();
  for (int off = 1; off < 256; off <<= 1) {
    int u = (t >= off) ? sm[t - off] : 0;
    __syncthreads();
    sm[t] += u;
    __syncthreads();
  }
  if (t < nb) partials[t] = sm[t] - v;  // exclusive
}

// local scan + block offset; fused dinv = rsqrt(count+1) and cursor = row_ptr.
__global__ __launch_bounds__(256) void block_scan_kernel(
    const int* __restrict__ counts, int n, const int* __restrict__ partials,
    int* __restrict__ row_ptr, float* __restrict__ dinv, int* __restrict__ cursor) {
  __shared__ int sm[256];
  const int t = threadIdx.x;
  const int base = blockIdx.x * 2048 + t * 8;
  int v[8];
  int s = 0;
#pragma unroll
  for (int k = 0; k < 8; ++k) {
    int i = base + k;
    v[k] = (i < n) ? counts[i] : 0;
    s += v[k];
  }
  sm[t] = s;
  __syncthreads();
  for (int off = 1; off < 256; off <<= 1) {
    int u = (t >= off) ? sm[t - off] : 0;
    __syncthreads();
    sm[t] += u;
    __syncthreads();
  }
  int run = sm[t] - s + partials[blockIdx.x];  // exclusive prefix for this thread
#pragma unroll
  for (int k = 0; k < 8; ++k) {
    int i = base + k;
    if (i < n) {
      row_ptr[i] = run;
      cursor[i] = run;
      dinv[i] = rsqrtf((float)(v[k] + 1));
      run += v[k];
      if (i == n - 1) row_ptr[n] = run;
    }
  }
}

// Scatter edges into CSR-by-dst (stores src ids)
__global__ void fill_kernel(const int* __restrict__ edges, int E,
                            const int* __restrict__ flag,
                            int* __restrict__ cursor, int* __restrict__ csr) {
  const int f = flag[0];
  const int stride = gridDim.x * blockDim.x;
  for (int e = blockIdx.x * blockDim.x + threadIdx.x; e < E; e += stride) {
    int s, d;
    if (f) { s = edges[2 * (size_t)e]; d = edges[2 * ((size_t)E + e)]; }
    else   { s = edges[e];             d = edges[(size_t)E + e]; }
    int pos = atomicAdd(&cursor[d], 1);
    csr[pos] = s;
  }
}

// out[r][c] = (sum_k A[r][k]*W[k][c]) * dinv[r]    (A: n x K, W: K x 64)
// 64x64 tile per 256-thread block, 4x4 register blocking, K-chunks of 32.
template <int K>
__global__ __launch_bounds__(256) void gemm_scale_kernel(
    const float* __restrict__ A, const float* __restrict__ W,
    const float* __restrict__ dinv, float* __restrict__ out, int n) {
  __shared__ float As[32][68];  // As[k][row]  (transposed stage, pad to 68)
  __shared__ float Bs[32][68];  // Bs[k][col]
  const int t = threadIdx.x;
  const int tr = t >> 4;        // 0..15 row group (rows tr*4..tr*4+3)
  const int tc = t & 15;        // 0..15 col group (cols tc*4..tc*4+3)
  const int row0 = blockIdx.x * 64;
  const int sr = t >> 2;        // 0..63 : row for A staging
  const int sk = (t & 3) << 3;  // 0,8,16,24 : k offset for A staging
  const int wkk = t >> 3;       // 0..31 : k for W staging
  const int wc = (t & 7) << 3;  // 0,8,..56 : col offset for W staging

  float acc[4][4] = {{0.f, 0.f, 0.f, 0.f}, {0.f, 0.f, 0.f, 0.f},
                     {0.f, 0.f, 0.f, 0.f}, {0.f, 0.f, 0.f, 0.f}};

  for (int k0 = 0; k0 < K; k0 += 32) {
    float4 a0 = make_float4(0.f, 0.f, 0.f, 0.f), a1 = a0;
    int r = row0 + sr;
    if (r < n) {
      a0 = *(const float4*)&A[(size_t)r * K + k0 + sk];
      a1 = *(const float4*)&A[(size_t)r * K + k0 + sk + 4];
    }
    float4 w0 = *(const float4*)&W[(size_t)(k0 + wkk) * 64 + wc];
    float4 w1 = *(const float4*)&W[(size_t)(k0 + wkk) * 64 + wc + 4];
    if (k0 != 0) __syncthreads();  // previous compute done before restaging
    As[sk + 0][sr] = a0.x; As[sk + 1][sr] = a0.y; As[sk + 2][sr] = a0.z; As[sk + 3][sr] = a0.w;
    As[sk + 4][sr] = a1.x; As[sk + 5][sr] = a1.y; As[sk + 6][sr] = a1.z; As[sk + 7][sr] = a1.w;
    *(float4*)&Bs[wkk][wc] = w0;
    *(float4*)&Bs[wkk][wc + 4] = w1;
    __syncthreads();
#pragma unroll
    for (int kk = 0; kk < 32; ++kk) {
      float4 a4 = *(const float4*)&As[kk][tr << 2];
      float4 b4 = *(const float4*)&Bs[kk][tc << 2];
      float av[4] = {a4.x, a4.y, a4.z, a4.w};
      float bv[4] = {b4.x, b4.y, b4.z, b4.w};
#pragma unroll
      for (int i = 0; i < 4; ++i)
#pragma unroll
        for (int j = 0; j < 4; ++j)
          acc[i][j] = fmaf(av[i], bv[j], acc[i][j]);
    }
  }
  __syncthreads();

#pragma unroll
  for (int i = 0; i < 4; ++i) {
    int r = row0 + (tr << 2) + i;
    if (r < n) {
      float s = dinv[r];
      float4 o;
      o.x = acc[i][0] * s; o.y = acc[i][1] * s;
      o.z = acc[i][2] * s; o.w = acc[i][3] * s;
      *(float4*)&out[(size_t)r * 64 + (tc << 2)] = o;
    }
  }
}

// One wave per dst node, lane = channel. acc = hs[d] (self loop) + sum hs[src].
// out = acc*dinv[d] + bias, optional relu.
template <int RELU>
__global__ __launch_bounds__(256) void agg_kernel(
    const float* __restrict__ hs, const int* __restrict__ row_ptr,
    const int* __restrict__ csr, const float* __restrict__ dinv,
    const float* __restrict__ bias, float* __restrict__ out, int n) {
  const int wave = blockIdx.x * 4 + ((int)threadIdx.x >> 6);
  const int lane = (int)threadIdx.x & 63;
  if (wave >= n) return;
  const int d = wave;
  const int start = row_ptr[d];
  const int end = row_ptr[d + 1];
  float acc = hs[(size_t)d * 64 + lane];  // self loop contribution
  int j = start;
  for (; j + 4 <= end; j += 4) {
    int s0 = csr[j], s1 = csr[j + 1], s2 = csr[j + 2], s3 = csr[j + 3];
    float v0 = hs[(size_t)s0 * 64 + lane];
    float v1 = hs[(size_t)s1 * 64 + lane];
    float v2 = hs[(size_t)s2 * 64 + lane];
    float v3 = hs[(size_t)s3 * 64 + lane];
    acc += v0; acc += v1; acc += v2; acc += v3;
  }
  for (; j < end; ++j) acc += hs[(size_t)csr[j] * 64 + lane];
  float v = acc * dinv[d] + bias[lane];
  if (RELU) v = fmaxf(v, 0.f);
  out[(size_t)d * 64 + lane] = v;
}

extern "C" void kernel_launch(void* const* d_in, const int* in_sizes, int n_in,
                              void* d_out, int out_size, void* d_ws, size_t ws_size,
                              hipStream_t stream) {
  const float* x  = (const float*)d_in[0];
  const int*   ei = (const int*)d_in[1];
  const float* W1 = (const float*)d_in[2];
  const float* b1 = (const float*)d_in[3];
  const float* W2 = (const float*)d_in[4];
  const float* b2 = (const float*)d_in[5];
  float* out = (float*)d_out;

  const int N = in_sizes[0] / 128;  // 100000
  const int E = in_sizes[1] / 2;    // 1600000 (element count is dtype-agnostic)

  char* ws = (char*)d_ws;
  size_t off = 0;
  auto take = [&](size_t bytes) -> void* {
    void* p = ws + off;
    off += (bytes + 255) & ~(size_t)255;
    return p;
  };
  int*   flag     = (int*)take(sizeof(int));
  int*   counts   = (int*)take((size_t)N * 4);
  int*   row_ptr  = (int*)take((size_t)(N + 1) * 4);
  int*   cursor   = (int*)take((size_t)N * 4);
  float* dinv     = (float*)take((size_t)N * 4);
  int*   partials = (int*)take(256 * 4);
  int*   csr      = (int*)take((size_t)E * 4);
  float* bufA     = (float*)take((size_t)N * 64 * 4);  // hs (scaled GEMM out)
  float* bufB     = (float*)take((size_t)N * 64 * 4);  // h (post layer-1)
  (void)ws_size; (void)n_in; (void)out_size;

  const int nb = (N + 2047) / 2048;  // 49 scan blocks

  (void)hipMemsetAsync(counts, 0, (size_t)N * 4, stream);
  detect_i64_kernel<<<1, 256, 0, stream>>>((const unsigned int*)ei, 4096, flag);
  count_kernel<<<2048, 256, 0, stream>>>(ei, E, flag, counts);
  partial_sum_kernel<<<nb, 256, 0, stream>>>(counts, N, partials);
  scan_partials_kernel<<<1, 256, 0, stream>>>(partials, nb);
  block_scan_kernel<<<nb, 256, 0, stream>>>(counts, N, partials, row_ptr, dinv, cursor);
  fill_kernel<<<2048, 256, 0, stream>>>(ei, E, flag, cursor, csr);

  // Layer 1: hs1 = (x @ W1) * dinv ; h = relu(dinv*(agg) + b1)
  gemm_scale_kernel<128><<<(N + 63) / 64, 256, 0, stream>>>(x, W1, dinv, bufA, N);
  agg_kernel<1><<<(N + 3) / 4, 256, 0, stream>>>(bufA, row_ptr, csr, dinv, b1, bufB, N);

  // Layer 2: hs2 = (h @ W2) * dinv ; out = dinv*(agg) + b2
  gemm_scale_kernel<64><<<(N + 63) / 64, 256, 0, stream>>>(bufB, W2, dinv, bufA, N);
  agg_kernel<0><<<(N + 3) / 4, 256, 0, stream>>>(bufA, row_ptr, csr, dinv, b2, out, N);
}

// Round 3
// 284.253 us; speedup vs baseline: 1.9997x; 1.4241x over previous
//
#include <hip/hip_runtime.h>

// ---------------------------------------------------------------------------
// 2-layer GCN: out = GCNConv2( relu(GCNConv1(x)) )
// GCNConv(x,W,b): h = x@W ; out[d] = dinv[d]*( sum_{s->d} h[s]*dinv[s] + h[d]*dinv[d] ) + b
// with dinv = rsqrt(in-degree + 1)  (self-loops added).
//
// CSR build: count (atomicAdd, records per-edge rank) -> 3-phase scan ->
// atomic-free fill (csr[row_ptr[d]+rank[e]] = s), fused with GEMM1 to overlap
// latency-bound scatter with VALU-bound dense work.
// ---------------------------------------------------------------------------

// Detect whether edge_index was stored as int64 (all high words of values <N
// are zero) or int32 (odd words are random node ids, nonzero w.h.p.).
__global__ void detect_i64_kernel(const unsigned int* __restrict__ w, int ncheck,
                                  int* __restrict__ flag) {
  __shared__ int nz;
  if (threadIdx.x == 0) nz = 0;
  __syncthreads();
  for (int i = threadIdx.x; i < ncheck; i += blockDim.x) {
    if (w[2 * i + 1] != 0u) nz = 1;
  }
  __syncthreads();
  if (threadIdx.x == 0) flag[0] = (nz == 0) ? 1 : 0;
}

// counts[d] += 1 for every edge dst d; rank[e] = arrival order within d.
__global__ void count_kernel(const int* __restrict__ edges, int E,
                             const int* __restrict__ flag, int* __restrict__ counts,
                             int* __restrict__ rank) {
  const int f = flag[0];
  const int stride = gridDim.x * blockDim.x;
  for (int e = blockIdx.x * blockDim.x + threadIdx.x; e < E; e += stride) {
    int d = f ? edges[2 * ((size_t)E + e)] : edges[(size_t)E + e];
    rank[e] = atomicAdd(&counts[d], 1);
  }
}

// ---- 3-phase device-wide exclusive scan over counts[0..n) ------------------
// chunk = 2048 elements / block (256 threads x 8).

__global__ __launch_bounds__(256) void partial_sum_kernel(
    const int* __restrict__ counts, int n, int* __restrict__ partials) {
  const int base = blockIdx.x * 2048 + (int)threadIdx.x * 8;
  int s = 0;
#pragma unroll
  for (int k = 0; k < 8; ++k) {
    int i = base + k;
    if (i < n) s += counts[i];
  }
#pragma unroll
  for (int off = 32; off; off >>= 1) s += __shfl_down(s, off, 64);
  __shared__ int ws[4];
  if ((threadIdx.x & 63) == 0) ws[threadIdx.x >> 6] = s;
  __syncthreads();
  if (threadIdx.x == 0) partials[blockIdx.x] = ws[0] + ws[1] + ws[2] + ws[3];
}

// single block, nb <= 256: partials[i] <- sum of partials[0..i)
__global__ __launch_bounds__(256) void scan_partials_kernel(int* __restrict__ partials, int nb) {
  __shared__ int sm[256];
  const int t = threadIdx.x;
  int v = (t < nb) ? partials[t] : 0;
  sm[t] = v;
  __syncthreads();
  for (int off = 1; off < 256; off <<= 1) {
    int u = (t >= off) ? sm[t - off] : 0;
    __syncthreads();
    sm[t] += u;
    __syncthreads();
  }
  if (t < nb) partials[t] = sm[t] - v;  // exclusive
}

// local scan + block offset; fused dinv = rsqrt(count+1).
__global__ __launch_bounds__(256) void block_scan_kernel(
    const int* __restrict__ counts, int n, const int* __restrict__ partials,
    int* __restrict__ row_ptr, float* __restrict__ dinv) {
  __shared__ int sm[256];
  const int t = threadIdx.x;
  const int base = blockIdx.x * 2048 + t * 8;
  int v[8];
  int s = 0;
#pragma unroll
  for (int k = 0; k < 8; ++k) {
    int i = base + k;
    v[k] = (i < n) ? counts[i] : 0;
    s += v[k];
  }
  sm[t] = s;
  __syncthreads();
  for (int off = 1; off < 256; off <<= 1) {
    int u = (t >= off) ? sm[t - off] : 0;
    __syncthreads();
    sm[t] += u;
    __syncthreads();
  }
  int run = sm[t] - s + partials[blockIdx.x];  // exclusive prefix for this thread
#pragma unroll
  for (int k = 0; k < 8; ++k) {
    int i = base + k;
    if (i < n) {
      row_ptr[i] = run;
      dinv[i] = rsqrtf((float)(v[k] + 1));
      run += v[k];
      if (i == n - 1) row_ptr[n] = run;
    }
  }
}

// Fused: blocks [0, gemm_blocks) do GEMM1 (hs = (A@W)*dinv), blocks
// [gemm_blocks, gemm_blocks+fill_blocks) do the atomic-free CSR fill.
// Both are ready after block_scan and independent -> CU-level overlap of
// VALU-bound GEMM with latency-bound scatter.
template <int K>
__global__ __launch_bounds__(256) void gemm_fill_kernel(
    const float* __restrict__ A, const float* __restrict__ W,
    const float* __restrict__ dinv, float* __restrict__ out, int n, int gemm_blocks,
    const int* __restrict__ edges, int E, const int* __restrict__ flag,
    const int* __restrict__ rank, const int* __restrict__ row_ptr,
    int* __restrict__ csr, int fill_blocks) {
  __shared__ float As[32][68];  // As[k][row]  (transposed stage, pad to 68)
  __shared__ float Bs[32][68];  // Bs[k][col]
  const int t = threadIdx.x;

  if ((int)blockIdx.x >= gemm_blocks) {
    // ---------------- fill path ----------------
    const int bid = (int)blockIdx.x - gemm_blocks;
    const int f = flag[0];
    const int stride = fill_blocks * 256;
    for (int e = bid * 256 + t; e < E; e += stride) {
      int s, d;
      if (f) { s = edges[2 * (size_t)e]; d = edges[2 * ((size_t)E + e)]; }
      else   { s = edges[e];             d = edges[(size_t)E + e]; }
      csr[row_ptr[d] + rank[e]] = s;
    }
    return;
  }

  // ---------------- GEMM path ----------------
  const int tr = t >> 4;        // 0..15 row group (rows tr*4..tr*4+3)
  const int tc = t & 15;        // 0..15 col group (cols tc*4..tc*4+3)
  const int row0 = blockIdx.x * 64;
  const int sr = t >> 2;        // 0..63 : row for A staging
  const int sk = (t & 3) << 3;  // 0,8,16,24 : k offset for A staging
  const int wkk = t >> 3;       // 0..31 : k for W staging
  const int wc = (t & 7) << 3;  // 0,8,..56 : col offset for W staging

  float acc[4][4] = {{0.f, 0.f, 0.f, 0.f}, {0.f, 0.f, 0.f, 0.f},
                     {0.f, 0.f, 0.f, 0.f}, {0.f, 0.f, 0.f, 0.f}};

  for (int k0 = 0; k0 < K; k0 += 32) {
    float4 a0 = make_float4(0.f, 0.f, 0.f, 0.f), a1 = a0;
    int r = row0 + sr;
    if (r < n) {
      a0 = *(const float4*)&A[(size_t)r * K + k0 + sk];
      a1 = *(const float4*)&A[(size_t)r * K + k0 + sk + 4];
    }
    float4 w0 = *(const float4*)&W[(size_t)(k0 + wkk) * 64 + wc];
    float4 w1 = *(const float4*)&W[(size_t)(k0 + wkk) * 64 + wc + 4];
    if (k0 != 0) __syncthreads();  // previous compute done before restaging
    As[sk + 0][sr] = a0.x; As[sk + 1][sr] = a0.y; As[sk + 2][sr] = a0.z; As[sk + 3][sr] = a0.w;
    As[sk + 4][sr] = a1.x; As[sk + 5][sr] = a1.y; As[sk + 6][sr] = a1.z; As[sk + 7][sr] = a1.w;
    *(float4*)&Bs[wkk][wc] = w0;
    *(float4*)&Bs[wkk][wc + 4] = w1;
    __syncthreads();
#pragma unroll
    for (int kk = 0; kk < 32; ++kk) {
      float4 a4 = *(const float4*)&As[kk][tr << 2];
      float4 b4 = *(const float4*)&Bs[kk][tc << 2];
      float av[4] = {a4.x, a4.y, a4.z, a4.w};
      float bv[4] = {b4.x, b4.y, b4.z, b4.w};
#pragma unroll
      for (int i = 0; i < 4; ++i)
#pragma unroll
        for (int j = 0; j < 4; ++j)
          acc[i][j] = fmaf(av[i], bv[j], acc[i][j]);
    }
  }
  __syncthreads();

#pragma unroll
  for (int i = 0; i < 4; ++i) {
    int r = row0 + (tr << 2) + i;
    if (r < n) {
      float s = dinv[r];
      float4 o;
      o.x = acc[i][0] * s; o.y = acc[i][1] * s;
      o.z = acc[i][2] * s; o.w = acc[i][3] * s;
      *(float4*)&out[(size_t)r * 64 + (tc << 2)] = o;
    }
  }
}

// Plain GEMM for layer 2 (no fill to fuse).
template <int K>
__global__ __launch_bounds__(256) void gemm_scale_kernel(
    const float* __restrict__ A, const float* __restrict__ W,
    const float* __restrict__ dinv, float* __restrict__ out, int n) {
  __shared__ float As[32][68];
  __shared__ float Bs[32][68];
  const int t = threadIdx.x;
  const int tr = t >> 4;
  const int tc = t & 15;
  const int row0 = blockIdx.x * 64;
  const int sr = t >> 2;
  const int sk = (t & 3) << 3;
  const int wkk = t >> 3;
  const int wc = (t & 7) << 3;

  float acc[4][4] = {{0.f, 0.f, 0.f, 0.f}, {0.f, 0.f, 0.f, 0.f},
                     {0.f, 0.f, 0.f, 0.f}, {0.f, 0.f, 0.f, 0.f}};

  for (int k0 = 0; k0 < K; k0 += 32) {
    float4 a0 = make_float4(0.f, 0.f, 0.f, 0.f), a1 = a0;
    int r = row0 + sr;
    if (r < n) {
      a0 = *(const float4*)&A[(size_t)r * K + k0 + sk];
      a1 = *(const float4*)&A[(size_t)r * K + k0 + sk + 4];
    }
    float4 w0 = *(const float4*)&W[(size_t)(k0 + wkk) * 64 + wc];
    float4 w1 = *(const float4*)&W[(size_t)(k0 + wkk) * 64 + wc + 4];
    if (k0 != 0) __syncthreads();
    As[sk + 0][sr] = a0.x; As[sk + 1][sr] = a0.y; As[sk + 2][sr] = a0.z; As[sk + 3][sr] = a0.w;
    As[sk + 4][sr] = a1.x; As[sk + 5][sr] = a1.y; As[sk + 6][sr] = a1.z; As[sk + 7][sr] = a1.w;
    *(float4*)&Bs[wkk][wc] = w0;
    *(float4*)&Bs[wkk][wc + 4] = w1;
    __syncthreads();
#pragma unroll
    for (int kk = 0; kk < 32; ++kk) {
      float4 a4 = *(const float4*)&As[kk][tr << 2];
      float4 b4 = *(const float4*)&Bs[kk][tc << 2];
      float av[4] = {a4.x, a4.y, a4.z, a4.w};
      float bv[4] = {b4.x, b4.y, b4.z, b4.w};
#pragma unroll
      for (int i = 0; i < 4; ++i)
#pragma unroll
        for (int j = 0; j < 4; ++j)
          acc[i][j] = fmaf(av[i], bv[j], acc[i][j]);
    }
  }
  __syncthreads();

#pragma unroll
  for (int i = 0; i < 4; ++i) {
    int r = row0 + (tr << 2) + i;
    if (r < n) {
      float s = dinv[r];
      float4 o;
      o.x = acc[i][0] * s; o.y = acc[i][1] * s;
      o.z = acc[i][2] * s; o.w = acc[i][3] * s;
      *(float4*)&out[(size_t)r * 64 + (tc << 2)] = o;
    }
  }
}

// One wave per dst node, lane = channel. acc = hs[d] (self loop) + sum hs[src].
// out = acc*dinv[d] + bias, optional relu.
template <int RELU>
__global__ __launch_bounds__(256) void agg_kernel(
    const float* __restrict__ hs, const int* __restrict__ row_ptr,
    const int* __restrict__ csr, const float* __restrict__ dinv,
    const float* __restrict__ bias, float* __restrict__ out, int n) {
  const int wave = blockIdx.x * 4 + ((int)threadIdx.x >> 6);
  const int lane = (int)threadIdx.x & 63;
  if (wave >= n) return;
  const int d = wave;
  const int start = row_ptr[d];
  const int end = row_ptr[d + 1];
  float acc = hs[(size_t)d * 64 + lane];  // self loop contribution
  int j = start;
  for (; j + 4 <= end; j += 4) {
    int s0 = csr[j], s1 = csr[j + 1], s2 = csr[j + 2], s3 = csr[j + 3];
    float v0 = hs[(size_t)s0 * 64 + lane];
    float v1 = hs[(size_t)s1 * 64 + lane];
    float v2 = hs[(size_t)s2 * 64 + lane];
    float v3 = hs[(size_t)s3 * 64 + lane];
    acc += v0; acc += v1; acc += v2; acc += v3;
  }
  for (; j < end; ++j) acc += hs[(size_t)csr[j] * 64 + lane];
  float v = acc * dinv[d] + bias[lane];
  if (RELU) v = fmaxf(v, 0.f);
  out[(size_t)d * 64 + lane] = v;
}

extern "C" void kernel_launch(void* const* d_in, const int* in_sizes, int n_in,
                              void* d_out, int out_size, void* d_ws, size_t ws_size,
                              hipStream_t stream) {
  const float* x  = (const float*)d_in[0];
  const int*   ei = (const int*)d_in[1];
  const float* W1 = (const float*)d_in[2];
  const float* b1 = (const float*)d_in[3];
  const float* W2 = (const float*)d_in[4];
  const float* b2 = (const float*)d_in[5];
  float* out = (float*)d_out;

  const int N = in_sizes[0] / 128;  // 100000
  const int E = in_sizes[1] / 2;    // 1600000

  char* ws = (char*)d_ws;
  size_t off = 0;
  auto take = [&](size_t bytes) -> void* {
    void* p = ws + off;
    off += (bytes + 255) & ~(size_t)255;
    return p;
  };
  int*   flag     = (int*)take(sizeof(int));
  int*   counts   = (int*)take((size_t)N * 4);
  int*   row_ptr  = (int*)take((size_t)(N + 1) * 4);
  float* dinv     = (float*)take((size_t)N * 4);
  int*   partials = (int*)take(256 * 4);
  int*   csr      = (int*)take((size_t)E * 4);
  float* bufA     = (float*)take((size_t)N * 64 * 4);  // hs (scaled GEMM out)
  float* bufB     = (float*)take((size_t)N * 64 * 4);  // h (post layer-1)
  int*   rank     = (int*)bufB;  // rank[E] aliases bufB (dead until agg1 writes it)
  (void)ws_size; (void)n_in; (void)out_size;

  const int nb = (N + 2047) / 2048;        // scan blocks
  const int g1 = (N + 63) / 64;            // gemm1 blocks
  const int g2 = (N + 63) / 64;            // gemm2 blocks
  const int FB = 1024;                     // fill blocks

  (void)hipMemsetAsync(counts, 0, (size_t)N * 4, stream);
  detect_i64_kernel<<<1, 256, 0, stream>>>((const unsigned int*)ei, 4096, flag);
  count_kernel<<<2048, 256, 0, stream>>>(ei, E, flag, counts, rank);
  partial_sum_kernel<<<nb, 256, 0, stream>>>(counts, N, partials);
  scan_partials_kernel<<<1, 256, 0, stream>>>(partials, nb);
  block_scan_kernel<<<nb, 256, 0, stream>>>(counts, N, partials, row_ptr, dinv);

  // Layer 1 GEMM fused with CSR fill (independent, overlap on CUs).
  gemm_fill_kernel<128><<<g1 + FB, 256, 0, stream>>>(
      x, W1, dinv, bufA, N, g1, ei, E, flag, rank, row_ptr, csr, FB);

  // h = relu(dinv*(agg hs1) + b1)   [overwrites rank's space -- rank is dead]
  agg_kernel<1><<<(N + 3) / 4, 256, 0, stream>>>(bufA, row_ptr, csr, dinv, b1, bufB, N);

  // Layer 2: hs2 = (h @ W2) * dinv ; out = dinv*(agg) + b2
  gemm_scale_kernel<64><<<g2, 256, 0, stream>>>(bufB, W2, dinv, bufA, N);
  agg_kernel<0><<<(N + 3) / 4, 256, 0, stream>>>(bufA, row_ptr, csr, dinv, b2, out, N);
}

// Round 4
// 282.170 us; speedup vs baseline: 2.0144x; 1.0074x over previous
//
#include <hip/hip_runtime.h>
#include <hip/hip_fp16.h>

// ---------------------------------------------------------------------------
// 2-layer GCN: out = GCNConv2( relu(GCNConv1(x)) )
// GCNConv(x,W,b): h = x@W ; out[d] = dinv[d]*( sum_{s->d} h[s]*dinv[s] + h[d]*dinv[d] ) + b
// dinv = rsqrt(in-degree + 1) (self-loops).
//
// Schedule: count(+rank) -> scan -> [CSR fill || gemm1 (unscaled f16)] ->
// agg1 (per-edge dinv, f16 gather) -> gemm2 (f16 scaled out) -> agg2.
// f16 intermediates halve the random-gather bytes (the measured bottleneck:
// 190 MB L2-miss fetch per agg at ~3 TB/s).
// ---------------------------------------------------------------------------

struct alignas(8) H4 { __half2 a, b; };
__device__ inline H4 pack4(float x, float y, float z, float w) {
  H4 r; r.a = __floats2half2_rn(x, y); r.b = __floats2half2_rn(z, w); return r;
}

// Detect whether edge_index was stored as int64 (all high words of values <N
// are zero) or int32 (odd words are random node ids, nonzero w.h.p.).
__global__ void detect_i64_kernel(const unsigned int* __restrict__ w, int ncheck,
                                  int* __restrict__ flag) {
  __shared__ int nz;
  if (threadIdx.x == 0) nz = 0;
  __syncthreads();
  for (int i = threadIdx.x; i < ncheck; i += blockDim.x) {
    if (w[2 * i + 1] != 0u) nz = 1;
  }
  __syncthreads();
  if (threadIdx.x == 0) flag[0] = (nz == 0) ? 1 : 0;
}

// counts[d] += 1 for every edge dst d; rank[e] = arrival order within d.
__global__ void count_kernel(const int* __restrict__ edges, int E,
                             const int* __restrict__ flag, int* __restrict__ counts,
                             int* __restrict__ rank) {
  const int f = flag[0];
  const int stride = gridDim.x * blockDim.x;
  for (int e = blockIdx.x * blockDim.x + threadIdx.x; e < E; e += stride) {
    int d = f ? edges[2 * ((size_t)E + e)] : edges[(size_t)E + e];
    rank[e] = atomicAdd(&counts[d], 1);
  }
}

// ---- 3-phase device-wide exclusive scan over counts[0..n) ------------------

__global__ __launch_bounds__(256) void partial_sum_kernel(
    const int* __restrict__ counts, int n, int* __restrict__ partials) {
  const int base = blockIdx.x * 2048 + (int)threadIdx.x * 8;
  int s = 0;
#pragma unroll
  for (int k = 0; k < 8; ++k) {
    int i = base + k;
    if (i < n) s += counts[i];
  }
#pragma unroll
  for (int off = 32; off; off >>= 1) s += __shfl_down(s, off, 64);
  __shared__ int ws[4];
  if ((threadIdx.x & 63) == 0) ws[threadIdx.x >> 6] = s;
  __syncthreads();
  if (threadIdx.x == 0) partials[blockIdx.x] = ws[0] + ws[1] + ws[2] + ws[3];
}

__global__ __launch_bounds__(256) void scan_partials_kernel(int* __restrict__ partials, int nb) {
  __shared__ int sm[256];
  const int t = threadIdx.x;
  int v = (t < nb) ? partials[t] : 0;
  sm[t] = v;
  __syncthreads();
  for (int off = 1; off < 256; off <<= 1) {
    int u = (t >= off) ? sm[t - off] : 0;
    __syncthreads();
    sm[t] += u;
    __syncthreads();
  }
  if (t < nb) partials[t] = sm[t] - v;  // exclusive
}

__global__ __launch_bounds__(256) void block_scan_kernel(
    const int* __restrict__ counts, int n, const int* __restrict__ partials,
    int* __restrict__ row_ptr, float* __restrict__ dinv) {
  __shared__ int sm[256];
  const int t = threadIdx.x;
  const int base = blockIdx.x * 2048 + t * 8;
  int v[8];
  int s = 0;
#pragma unroll
  for (int k = 0; k < 8; ++k) {
    int i = base + k;
    v[k] = (i < n) ? counts[i] : 0;
    s += v[k];
  }
  sm[t] = s;
  __syncthreads();
  for (int off = 1; off < 256; off <<= 1) {
    int u = (t >= off) ? sm[t - off] : 0;
    __syncthreads();
    sm[t] += u;
    __syncthreads();
  }
  int run = sm[t] - s + partials[blockIdx.x];
#pragma unroll
  for (int k = 0; k < 8; ++k) {
    int i = base + k;
    if (i < n) {
      row_ptr[i] = run;
      dinv[i] = rsqrtf((float)(v[k] + 1));
      run += v[k];
      if (i == n - 1) row_ptr[n] = run;
    }
  }
}

// Fused: blocks [0, fill_blocks) do the atomic-free CSR fill; the rest do
// GEMM1: g = x @ W1, UNSCALED, stored f16 (graph-independent -> overlaps the
// latency-bound scatter with VALU-bound dense work in one launch).
__global__ __launch_bounds__(256) void fill_gemm_kernel(
    const int* __restrict__ edges, int E, const int* __restrict__ flag,
    const int* __restrict__ rank, const int* __restrict__ row_ptr,
    int* __restrict__ csr, int fill_blocks,
    const float* __restrict__ A, const float* __restrict__ W,
    __half* __restrict__ g, int n) {
  __shared__ float As[32][68];  // As[k][row]
  __shared__ float Bs[32][68];  // Bs[k][col]
  const int t = threadIdx.x;

  if ((int)blockIdx.x < fill_blocks) {
    const int f = flag[0];
    const int stride = fill_blocks * 256;
    for (int e = (int)blockIdx.x * 256 + t; e < E; e += stride) {
      int s, d;
      if (f) { s = edges[2 * (size_t)e]; d = edges[2 * ((size_t)E + e)]; }
      else   { s = edges[e];             d = edges[(size_t)E + e]; }
      csr[row_ptr[d] + rank[e]] = s;
    }
    return;
  }

  constexpr int K = 128;
  const int tr = t >> 4;
  const int tc = t & 15;
  const int row0 = ((int)blockIdx.x - fill_blocks) * 64;
  const int sr = t >> 2;
  const int sk = (t & 3) << 3;
  const int wkk = t >> 3;
  const int wc = (t & 7) << 3;

  float acc[4][4] = {{0.f, 0.f, 0.f, 0.f}, {0.f, 0.f, 0.f, 0.f},
                     {0.f, 0.f, 0.f, 0.f}, {0.f, 0.f, 0.f, 0.f}};

  for (int k0 = 0; k0 < K; k0 += 32) {
    float4 a0 = make_float4(0.f, 0.f, 0.f, 0.f), a1 = a0;
    int r = row0 + sr;
    if (r < n) {
      a0 = *(const float4*)&A[(size_t)r * K + k0 + sk];
      a1 = *(const float4*)&A[(size_t)r * K + k0 + sk + 4];
    }
    float4 w0 = *(const float4*)&W[(size_t)(k0 + wkk) * 64 + wc];
    float4 w1 = *(const float4*)&W[(size_t)(k0 + wkk) * 64 + wc + 4];
    if (k0 != 0) __syncthreads();
    As[sk + 0][sr] = a0.x; As[sk + 1][sr] = a0.y; As[sk + 2][sr] = a0.z; As[sk + 3][sr] = a0.w;
    As[sk + 4][sr] = a1.x; As[sk + 5][sr] = a1.y; As[sk + 6][sr] = a1.z; As[sk + 7][sr] = a1.w;
    *(float4*)&Bs[wkk][wc] = w0;
    *(float4*)&Bs[wkk][wc + 4] = w1;
    __syncthreads();
#pragma unroll
    for (int kk = 0; kk < 32; ++kk) {
      float4 a4 = *(const float4*)&As[kk][tr << 2];
      float4 b4 = *(const float4*)&Bs[kk][tc << 2];
      float av[4] = {a4.x, a4.y, a4.z, a4.w};
      float bv[4] = {b4.x, b4.y, b4.z, b4.w};
#pragma unroll
      for (int i = 0; i < 4; ++i)
#pragma unroll
        for (int j = 0; j < 4; ++j)
          acc[i][j] = fmaf(av[i], bv[j], acc[i][j]);
    }
  }
  __syncthreads();

#pragma unroll
  for (int i = 0; i < 4; ++i) {
    int r = row0 + (tr << 2) + i;
    if (r < n)
      *(H4*)&g[(size_t)r * 64 + (tc << 2)] = pack4(acc[i][0], acc[i][1], acc[i][2], acc[i][3]);
  }
}

// GEMM2: hs2 = (h @ W2) * dinv[row], stored f16. K = 64.
__global__ __launch_bounds__(256) void gemm2_kernel(
    const float* __restrict__ A, const float* __restrict__ W,
    const float* __restrict__ dinv, __half* __restrict__ out, int n) {
  __shared__ float As[32][68];
  __shared__ float Bs[32][68];
  constexpr int K = 64;
  const int t = threadIdx.x;
  const int tr = t >> 4;
  const int tc = t & 15;
  const int row0 = blockIdx.x * 64;
  const int sr = t >> 2;
  const int sk = (t & 3) << 3;
  const int wkk = t >> 3;
  const int wc = (t & 7) << 3;

  float acc[4][4] = {{0.f, 0.f, 0.f, 0.f}, {0.f, 0.f, 0.f, 0.f},
                     {0.f, 0.f, 0.f, 0.f}, {0.f, 0.f, 0.f, 0.f}};

  for (int k0 = 0; k0 < K; k0 += 32) {
    float4 a0 = make_float4(0.f, 0.f, 0.f, 0.f), a1 = a0;
    int r = row0 + sr;
    if (r < n) {
      a0 = *(const float4*)&A[(size_t)r * K + k0 + sk];
      a1 = *(const float4*)&A[(size_t)r * K + k0 + sk + 4];
    }
    float4 w0 = *(const float4*)&W[(size_t)(k0 + wkk) * 64 + wc];
    float4 w1 = *(const float4*)&W[(size_t)(k0 + wkk) * 64 + wc + 4];
    if (k0 != 0) __syncthreads();
    As[sk + 0][sr] = a0.x; As[sk + 1][sr] = a0.y; As[sk + 2][sr] = a0.z; As[sk + 3][sr] = a0.w;
    As[sk + 4][sr] = a1.x; As[sk + 5][sr] = a1.y; As[sk + 6][sr] = a1.z; As[sk + 7][sr] = a1.w;
    *(float4*)&Bs[wkk][wc] = w0;
    *(float4*)&Bs[wkk][wc + 4] = w1;
    __syncthreads();
#pragma unroll
    for (int kk = 0; kk < 32; ++kk) {
      float4 a4 = *(const float4*)&As[kk][tr << 2];
      float4 b4 = *(const float4*)&Bs[kk][tc << 2];
      float av[4] = {a4.x, a4.y, a4.z, a4.w};
      float bv[4] = {b4.x, b4.y, b4.z, b4.w};
#pragma unroll
      for (int i = 0; i < 4; ++i)
#pragma unroll
        for (int j = 0; j < 4; ++j)
          acc[i][j] = fmaf(av[i], bv[j], acc[i][j]);
    }
  }
  __syncthreads();

#pragma unroll
  for (int i = 0; i < 4; ++i) {
    int r = row0 + (tr << 2) + i;
    if (r < n) {
      float s = dinv[r];
      *(H4*)&out[(size_t)r * 64 + (tc << 2)] =
          pack4(acc[i][0] * s, acc[i][1] * s, acc[i][2] * s, acc[i][3] * s);
    }
  }
}

// One wave per dst node, lane = channel, f16 gathers (128 B/row).
// EDGE_SCALE: input is unscaled (layer 1) -> multiply each gather by dinv[s],
// self term by dinv[d]. Otherwise input rows are pre-scaled (layer 2).
template <bool EDGE_SCALE, bool RELU>
__global__ __launch_bounds__(256) void agg_kernel(
    const __half* __restrict__ hs, const int* __restrict__ row_ptr,
    const int* __restrict__ csr, const float* __restrict__ dinv,
    const float* __restrict__ bias, float* __restrict__ out, int n) {
  const int d = blockIdx.x * 4 + ((int)threadIdx.x >> 6);
  const int lane = (int)threadIdx.x & 63;
  if (d >= n) return;
  const int start = row_ptr[d];
  const int end = row_ptr[d + 1];
  const float dd = dinv[d];
  float self = __half2float(hs[(size_t)d * 64 + lane]);
  float acc = EDGE_SCALE ? dd * self : self;
  int j = start;
  for (; j + 4 <= end; j += 4) {
    int s0 = csr[j], s1 = csr[j + 1], s2 = csr[j + 2], s3 = csr[j + 3];
    float v0 = __half2float(hs[(size_t)s0 * 64 + lane]);
    float v1 = __half2float(hs[(size_t)s1 * 64 + lane]);
    float v2 = __half2float(hs[(size_t)s2 * 64 + lane]);
    float v3 = __half2float(hs[(size_t)s3 * 64 + lane]);
    if (EDGE_SCALE) {
      acc = fmaf(dinv[s0], v0, acc);
      acc = fmaf(dinv[s1], v1, acc);
      acc = fmaf(dinv[s2], v2, acc);
      acc = fmaf(dinv[s3], v3, acc);
    } else {
      acc += v0; acc += v1; acc += v2; acc += v3;
    }
  }
  for (; j < end; ++j) {
    int s = csr[j];
    float v = __half2float(hs[(size_t)s * 64 + lane]);
    acc = EDGE_SCALE ? fmaf(dinv[s], v, acc) : (acc + v);
  }
  float v = acc * dd + bias[lane];
  if (RELU) v = fmaxf(v, 0.f);
  out[(size_t)d * 64 + lane] = v;
}

extern "C" void kernel_launch(void* const* d_in, const int* in_sizes, int n_in,
                              void* d_out, int out_size, void* d_ws, size_t ws_size,
                              hipStream_t stream) {
  const float* x  = (const float*)d_in[0];
  const int*   ei = (const int*)d_in[1];
  const float* W1 = (const float*)d_in[2];
  const float* b1 = (const float*)d_in[3];
  const float* W2 = (const float*)d_in[4];
  const float* b2 = (const float*)d_in[5];
  float* out = (float*)d_out;

  const int N = in_sizes[0] / 128;  // 100000
  const int E = in_sizes[1] / 2;    // 1600000

  char* ws = (char*)d_ws;
  size_t off = 0;
  auto take = [&](size_t bytes) -> void* {
    void* p = ws + off;
    off += (bytes + 255) & ~(size_t)255;
    return p;
  };
  int*    flag     = (int*)take(sizeof(int));
  int*    counts   = (int*)take((size_t)N * 4);
  int*    row_ptr  = (int*)take((size_t)(N + 1) * 4);
  float*  dinv     = (float*)take((size_t)N * 4);
  int*    partials = (int*)take(256 * 4);
  int*    csr      = (int*)take((size_t)E * 4);
  __half* hsf      = (__half*)take((size_t)N * 64 * 2);  // f16 gather buffer (both layers)
  float*  h        = (float*)take((size_t)N * 64 * 4);   // post layer-1 activations
  int*    rank     = (int*)h;  // rank[E] aliases h (dead until agg1 writes it)
  (void)ws_size; (void)n_in; (void)out_size;

  const int nb = (N + 2047) / 2048;  // scan blocks
  const int g1 = (N + 63) / 64;      // gemm blocks
  const int FB = 1024;               // fill blocks

  (void)hipMemsetAsync(counts, 0, (size_t)N * 4, stream);
  detect_i64_kernel<<<1, 256, 0, stream>>>((const unsigned int*)ei, 4096, flag);
  count_kernel<<<2048, 256, 0, stream>>>(ei, E, flag, counts, rank);
  partial_sum_kernel<<<nb, 256, 0, stream>>>(counts, N, partials);
  scan_partials_kernel<<<1, 256, 0, stream>>>(partials, nb);
  block_scan_kernel<<<nb, 256, 0, stream>>>(counts, N, partials, row_ptr, dinv);

  // CSR fill || g = x@W1 (unscaled f16) in one launch.
  fill_gemm_kernel<<<FB + g1, 256, 0, stream>>>(
      ei, E, flag, rank, row_ptr, csr, FB, x, W1, hsf, N);

  // h = relu(dinv[d]*(sum dinv[s]*g[s] + dinv[d]*g[d]) + b1)
  agg_kernel<true, true><<<(N + 3) / 4, 256, 0, stream>>>(
      hsf, row_ptr, csr, dinv, b1, h, N);

  // hs2 = (h @ W2) * dinv  (f16)
  gemm2_kernel<<<g1, 256, 0, stream>>>(h, W2, dinv, hsf, N);

  // out = dinv[d]*(sum hs2[s] + hs2[d]) + b2
  agg_kernel<false, false><<<(N + 3) / 4, 256, 0, stream>>>(
      hsf, row_ptr, csr, dinv, b2, out, N);
}

// Round 5
// 248.489 us; speedup vs baseline: 2.2875x; 1.1355x over previous
//
#include <hip/hip_runtime.h>
#include <hip/hip_fp16.h>

// ---------------------------------------------------------------------------
// 2-layer GCN: out = GCNConv2( relu(GCNConv1(x)) )
// GCNConv(x,W,b): h = x@W ; out[d] = dinv[d]*( sum_{s->d} h[s]*dinv[s] + h[d]*dinv[d] ) + b
// dinv = rsqrt(in-degree + 1) (self-loops).
//
// Schedule: count(+rank) -> scan -> [CSR fill || gemm1 (unscaled f16)] ->
// agg1 -> gemm2 -> agg2.
// agg: 4 dst nodes per wave (16 lanes x 8B = one 128B f16 row per quarter):
// 4x fewer vmem instructions per edge, 4x more bytes in flight per wave
// (the measured bottleneck was gather latency/issue, not bandwidth).
// ---------------------------------------------------------------------------

struct alignas(8) H4 { __half2 a, b; };
__device__ inline H4 pack4(float x, float y, float z, float w) {
  H4 r; r.a = __floats2half2_rn(x, y); r.b = __floats2half2_rn(z, w); return r;
}

// Detect whether edge_index was stored as int64 (all high words of values <N
// are zero) or int32 (odd words are random node ids, nonzero w.h.p.).
__global__ void detect_i64_kernel(const unsigned int* __restrict__ w, int ncheck,
                                  int* __restrict__ flag) {
  __shared__ int nz;
  if (threadIdx.x == 0) nz = 0;
  __syncthreads();
  for (int i = threadIdx.x; i < ncheck; i += blockDim.x) {
    if (w[2 * i + 1] != 0u) nz = 1;
  }
  __syncthreads();
  if (threadIdx.x == 0) flag[0] = (nz == 0) ? 1 : 0;
}

// counts[d] += 1 for every edge dst d; rank[e] = arrival order within d.
__global__ void count_kernel(const int* __restrict__ edges, int E,
                             const int* __restrict__ flag, int* __restrict__ counts,
                             int* __restrict__ rank) {
  const int f = flag[0];
  const int stride = gridDim.x * blockDim.x;
  for (int e = blockIdx.x * blockDim.x + threadIdx.x; e < E; e += stride) {
    int d = f ? edges[2 * ((size_t)E + e)] : edges[(size_t)E + e];
    rank[e] = atomicAdd(&counts[d], 1);
  }
}

// ---- 3-phase device-wide exclusive scan over counts[0..n) ------------------

__global__ __launch_bounds__(256) void partial_sum_kernel(
    const int* __restrict__ counts, int n, int* __restrict__ partials) {
  const int base = blockIdx.x * 2048 + (int)threadIdx.x * 8;
  int s = 0;
#pragma unroll
  for (int k = 0; k < 8; ++k) {
    int i = base + k;
    if (i < n) s += counts[i];
  }
#pragma unroll
  for (int off = 32; off; off >>= 1) s += __shfl_down(s, off, 64);
  __shared__ int ws[4];
  if ((threadIdx.x & 63) == 0) ws[threadIdx.x >> 6] = s;
  __syncthreads();
  if (threadIdx.x == 0) partials[blockIdx.x] = ws[0] + ws[1] + ws[2] + ws[3];
}

__global__ __launch_bounds__(256) void scan_partials_kernel(int* __restrict__ partials, int nb) {
  __shared__ int sm[256];
  const int t = threadIdx.x;
  int v = (t < nb) ? partials[t] : 0;
  sm[t] = v;
  __syncthreads();
  for (int off = 1; off < 256; off <<= 1) {
    int u = (t >= off) ? sm[t - off] : 0;
    __syncthreads();
    sm[t] += u;
    __syncthreads();
  }
  if (t < nb) partials[t] = sm[t] - v;  // exclusive
}

__global__ __launch_bounds__(256) void block_scan_kernel(
    const int* __restrict__ counts, int n, const int* __restrict__ partials,
    int* __restrict__ row_ptr, float* __restrict__ dinv) {
  __shared__ int sm[256];
  const int t = threadIdx.x;
  const int base = blockIdx.x * 2048 + t * 8;
  int v[8];
  int s = 0;
#pragma unroll
  for (int k = 0; k < 8; ++k) {
    int i = base + k;
    v[k] = (i < n) ? counts[i] : 0;
    s += v[k];
  }
  sm[t] = s;
  __syncthreads();
  for (int off = 1; off < 256; off <<= 1) {
    int u = (t >= off) ? sm[t - off] : 0;
    __syncthreads();
    sm[t] += u;
    __syncthreads();
  }
  int run = sm[t] - s + partials[blockIdx.x];
#pragma unroll
  for (int k = 0; k < 8; ++k) {
    int i = base + k;
    if (i < n) {
      row_ptr[i] = run;
      dinv[i] = rsqrtf((float)(v[k] + 1));
      run += v[k];
      if (i == n - 1) row_ptr[n] = run;
    }
  }
}

// Fused: blocks [0, fill_blocks) do the atomic-free CSR fill; the rest do
// GEMM1: g = x @ W1, UNSCALED, stored f16.
__global__ __launch_bounds__(256) void fill_gemm_kernel(
    const int* __restrict__ edges, int E, const int* __restrict__ flag,
    const int* __restrict__ rank, const int* __restrict__ row_ptr,
    int* __restrict__ csr, int fill_blocks,
    const float* __restrict__ A, const float* __restrict__ W,
    __half* __restrict__ g, int n) {
  __shared__ float As[32][68];  // As[k][row]
  __shared__ float Bs[32][68];  // Bs[k][col]
  const int t = threadIdx.x;

  if ((int)blockIdx.x < fill_blocks) {
    const int f = flag[0];
    const int stride = fill_blocks * 256;
    for (int e = (int)blockIdx.x * 256 + t; e < E; e += stride) {
      int s, d;
      if (f) { s = edges[2 * (size_t)e]; d = edges[2 * ((size_t)E + e)]; }
      else   { s = edges[e];             d = edges[(size_t)E + e]; }
      csr[row_ptr[d] + rank[e]] = s;
    }
    return;
  }

  constexpr int K = 128;
  const int tr = t >> 4;
  const int tc = t & 15;
  const int row0 = ((int)blockIdx.x - fill_blocks) * 64;
  const int sr = t >> 2;
  const int sk = (t & 3) << 3;
  const int wkk = t >> 3;
  const int wc = (t & 7) << 3;

  float acc[4][4] = {{0.f, 0.f, 0.f, 0.f}, {0.f, 0.f, 0.f, 0.f},
                     {0.f, 0.f, 0.f, 0.f}, {0.f, 0.f, 0.f, 0.f}};

  for (int k0 = 0; k0 < K; k0 += 32) {
    float4 a0 = make_float4(0.f, 0.f, 0.f, 0.f), a1 = a0;
    int r = row0 + sr;
    if (r < n) {
      a0 = *(const float4*)&A[(size_t)r * K + k0 + sk];
      a1 = *(const float4*)&A[(size_t)r * K + k0 + sk + 4];
    }
    float4 w0 = *(const float4*)&W[(size_t)(k0 + wkk) * 64 + wc];
    float4 w1 = *(const float4*)&W[(size_t)(k0 + wkk) * 64 + wc + 4];
    if (k0 != 0) __syncthreads();
    As[sk + 0][sr] = a0.x; As[sk + 1][sr] = a0.y; As[sk + 2][sr] = a0.z; As[sk + 3][sr] = a0.w;
    As[sk + 4][sr] = a1.x; As[sk + 5][sr] = a1.y; As[sk + 6][sr] = a1.z; As[sk + 7][sr] = a1.w;
    *(float4*)&Bs[wkk][wc] = w0;
    *(float4*)&Bs[wkk][wc + 4] = w1;
    __syncthreads();
#pragma unroll
    for (int kk = 0; kk < 32; ++kk) {
      float4 a4 = *(const float4*)&As[kk][tr << 2];
      float4 b4 = *(const float4*)&Bs[kk][tc << 2];
      float av[4] = {a4.x, a4.y, a4.z, a4.w};
      float bv[4] = {b4.x, b4.y, b4.z, b4.w};
#pragma unroll
      for (int i = 0; i < 4; ++i)
#pragma unroll
        for (int j = 0; j < 4; ++j)
          acc[i][j] = fmaf(av[i], bv[j], acc[i][j]);
    }
  }
  __syncthreads();

#pragma unroll
  for (int i = 0; i < 4; ++i) {
    int r = row0 + (tr << 2) + i;
    if (r < n)
      *(H4*)&g[(size_t)r * 64 + (tc << 2)] = pack4(acc[i][0], acc[i][1], acc[i][2], acc[i][3]);
  }
}

// GEMM2: hs2 = (h @ W2) * dinv[row], stored f16. K = 64.
__global__ __launch_bounds__(256) void gemm2_kernel(
    const float* __restrict__ A, const float* __restrict__ W,
    const float* __restrict__ dinv, __half* __restrict__ out, int n) {
  __shared__ float As[32][68];
  __shared__ float Bs[32][68];
  constexpr int K = 64;
  const int t = threadIdx.x;
  const int tr = t >> 4;
  const int tc = t & 15;
  const int row0 = blockIdx.x * 64;
  const int sr = t >> 2;
  const int sk = (t & 3) << 3;
  const int wkk = t >> 3;
  const int wc = (t & 7) << 3;

  float acc[4][4] = {{0.f, 0.f, 0.f, 0.f}, {0.f, 0.f, 0.f, 0.f},
                     {0.f, 0.f, 0.f, 0.f}, {0.f, 0.f, 0.f, 0.f}};

  for (int k0 = 0; k0 < K; k0 += 32) {
    float4 a0 = make_float4(0.f, 0.f, 0.f, 0.f), a1 = a0;
    int r = row0 + sr;
    if (r < n) {
      a0 = *(const float4*)&A[(size_t)r * K + k0 + sk];
      a1 = *(const float4*)&A[(size_t)r * K + k0 + sk + 4];
    }
    float4 w0 = *(const float4*)&W[(size_t)(k0 + wkk) * 64 + wc];
    float4 w1 = *(const float4*)&W[(size_t)(k0 + wkk) * 64 + wc + 4];
    if (k0 != 0) __syncthreads();
    As[sk + 0][sr] = a0.x; As[sk + 1][sr] = a0.y; As[sk + 2][sr] = a0.z; As[sk + 3][sr] = a0.w;
    As[sk + 4][sr] = a1.x; As[sk + 5][sr] = a1.y; As[sk + 6][sr] = a1.z; As[sk + 7][sr] = a1.w;
    *(float4*)&Bs[wkk][wc] = w0;
    *(float4*)&Bs[wkk][wc + 4] = w1;
    __syncthreads();
#pragma unroll
    for (int kk = 0; kk < 32; ++kk) {
      float4 a4 = *(const float4*)&As[kk][tr << 2];
      float4 b4 = *(const float4*)&Bs[kk][tc << 2];
      float av[4] = {a4.x, a4.y, a4.z, a4.w};
      float bv[4] = {b4.x, b4.y, b4.z, b4.w};
#pragma unroll
      for (int i = 0; i < 4; ++i)
#pragma unroll
        for (int j = 0; j < 4; ++j)
          acc[i][j] = fmaf(av[i], bv[j], acc[i][j]);
    }
  }
  __syncthreads();

#pragma unroll
  for (int i = 0; i < 4; ++i) {
    int r = row0 + (tr << 2) + i;
    if (r < n) {
      float s = dinv[r];
      *(H4*)&out[(size_t)r * 64 + (tc << 2)] =
          pack4(acc[i][0] * s, acc[i][1] * s, acc[i][2] * s, acc[i][3] * s);
    }
  }
}

// Aggregation: 4 dst nodes per wave. Quarter q (16 lanes) owns node
// d = wid*4+q; lane ql covers channels [ql*4, ql*4+4) via one 8B H4 load, so
// each gather instruction fetches 4 random 128B rows (512B). Unroll 4 with
// predicated (weight=0) slots for degree imbalance within the wave.
template <bool EDGE_SCALE, bool RELU>
__global__ __launch_bounds__(256) void agg_kernel(
    const __half* __restrict__ hs, const int* __restrict__ row_ptr,
    const int* __restrict__ csr, const float* __restrict__ dinv,
    const float* __restrict__ bias, float* __restrict__ out, int n) {
  const int wid = blockIdx.x * 4 + ((int)threadIdx.x >> 6);
  if (wid * 4 >= n) return;
  const int lane = (int)threadIdx.x & 63;
  const int q = lane >> 4;   // quarter 0..3 -> node
  const int ql = lane & 15;  // lane in quarter -> channel group
  const int d = wid * 4 + q;
  const bool active = d < n;
  const int dc = active ? d : n - 1;

  const int start = row_ptr[dc];
  const int end = active ? row_ptr[dc + 1] : start;
  const float dd = dinv[dc];

  H4 sv = *(const H4*)&hs[(size_t)dc * 64 + (ql << 2)];
  float2 s01 = __half22float2(sv.a), s23 = __half22float2(sv.b);
  const float ws = EDGE_SCALE ? dd : 1.f;
  float a0 = ws * s01.x, a1 = ws * s01.y, a2 = ws * s23.x, a3 = ws * s23.y;

  for (int j = start; __any(j < end); j += 4) {
#pragma unroll
    for (int u = 0; u < 4; ++u) {
      const bool p = (j + u) < end;
      const int s = p ? csr[j + u] : dc;
      H4 v = *(const H4*)&hs[(size_t)s * 64 + (ql << 2)];
      float w = p ? (EDGE_SCALE ? dinv[s] : 1.f) : 0.f;
      float2 f = __half22float2(v.a), g = __half22float2(v.b);
      a0 = fmaf(w, f.x, a0); a1 = fmaf(w, f.y, a1);
      a2 = fmaf(w, g.x, a2); a3 = fmaf(w, g.y, a3);
    }
  }

  if (active) {
    const float4 b4 = *(const float4*)&bias[ql << 2];
    float4 o;
    o.x = fmaf(a0, dd, b4.x); o.y = fmaf(a1, dd, b4.y);
    o.z = fmaf(a2, dd, b4.z); o.w = fmaf(a3, dd, b4.w);
    if (RELU) {
      o.x = fmaxf(o.x, 0.f); o.y = fmaxf(o.y, 0.f);
      o.z = fmaxf(o.z, 0.f); o.w = fmaxf(o.w, 0.f);
    }
    *(float4*)&out[(size_t)d * 64 + (ql << 2)] = o;
  }
}

extern "C" void kernel_launch(void* const* d_in, const int* in_sizes, int n_in,
                              void* d_out, int out_size, void* d_ws, size_t ws_size,
                              hipStream_t stream) {
  const float* x  = (const float*)d_in[0];
  const int*   ei = (const int*)d_in[1];
  const float* W1 = (const float*)d_in[2];
  const float* b1 = (const float*)d_in[3];
  const float* W2 = (const float*)d_in[4];
  const float* b2 = (const float*)d_in[5];
  float* out = (float*)d_out;

  const int N = in_sizes[0] / 128;  // 100000
  const int E = in_sizes[1] / 2;    // 1600000

  char* ws = (char*)d_ws;
  size_t off = 0;
  auto take = [&](size_t bytes) -> void* {
    void* p = ws + off;
    off += (bytes + 255) & ~(size_t)255;
    return p;
  };
  int*    flag     = (int*)take(sizeof(int));
  int*    counts   = (int*)take((size_t)N * 4);
  int*    row_ptr  = (int*)take((size_t)(N + 1) * 4);
  float*  dinv     = (float*)take((size_t)N * 4);
  int*    partials = (int*)take(256 * 4);
  int*    csr      = (int*)take((size_t)E * 4);
  __half* hsf      = (__half*)take((size_t)N * 64 * 2);  // f16 gather buffer
  float*  h        = (float*)take((size_t)N * 64 * 4);   // post layer-1 activations
  int*    rank     = (int*)h;  // rank[E] aliases h (dead until agg1 writes it)
  (void)ws_size; (void)n_in; (void)out_size;

  const int nb = (N + 2047) / 2048;  // scan blocks
  const int g1 = (N + 63) / 64;      // gemm blocks
  const int FB = 1024;               // fill blocks

  (void)hipMemsetAsync(counts, 0, (size_t)N * 4, stream);
  detect_i64_kernel<<<1, 256, 0, stream>>>((const unsigned int*)ei, 4096, flag);
  count_kernel<<<2048, 256, 0, stream>>>(ei, E, flag, counts, rank);
  partial_sum_kernel<<<nb, 256, 0, stream>>>(counts, N, partials);
  scan_partials_kernel<<<1, 256, 0, stream>>>(partials, nb);
  block_scan_kernel<<<nb, 256, 0, stream>>>(counts, N, partials, row_ptr, dinv);

  // CSR fill || g = x@W1 (unscaled f16) in one launch.
  fill_gemm_kernel<<<FB + g1, 256, 0, stream>>>(
      ei, E, flag, rank, row_ptr, csr, FB, x, W1, hsf, N);

  // h = relu(dinv[d]*(sum dinv[s]*g[s] + dinv[d]*g[d]) + b1)
  agg_kernel<true, true><<<(N + 15) / 16, 256, 0, stream>>>(
      hsf, row_ptr, csr, dinv, b1, h, N);

  // hs2 = (h @ W2) * dinv  (f16)
  gemm2_kernel<<<g1, 256, 0, stream>>>(h, W2, dinv, hsf, N);

  // out = dinv[d]*(sum hs2[s] + hs2[d]) + b2
  agg_kernel<false, false><<<(N + 15) / 16, 256, 0, stream>>>(
      hsf, row_ptr, csr, dinv, b2, out, N);
}